// Round 6
// baseline (78.231 us; speedup 1.0000x reference)
//
#include <hip/hip_runtime.h>

// ParaModel_69664369541839: match = v1 @ v2^T [B,L1,L2]; masked row/col max;
// s = -max/100 masked; softmax; attention-pool p1,p2; cosine(p1,p2).
// B=128, L1=L2=256, D=768, fp32 in/out.
//
// R6: K1 = fp16-in-LDS (R5's fp32 staging made the LDS pipe ~70% of the
// critical path: 12 b128 reads/thread/iter + DMA writes + 5.7M conflict cyc)
// + T14 async reg-staging (GLOAD(kt+1) issued before compute(kt), cvt+ds_write
// after — global latency hides under MFMA). One barrier per iteration, BK=64.
// LDS row stride 72 halves (144B): hand-verified uniform bank distribution
// (8 lanes per 4-bank group = b128 floor) for both read and write patterns.
// __launch_bounds__(512,2): R3's (512,4) capped VGPR at 64 and the allocator
// killed the prefetch — that was the real R3 failure.

#define B_   128
#define L_   256
#define D_   768
#define NEGV (-10000.0f)

typedef _Float16 f16x8 __attribute__((ext_vector_type(8)));
typedef __fp16   h16x2 __attribute__((ext_vector_type(2)));
typedef float    f32x4 __attribute__((ext_vector_type(4)));

#define BT   128          // l1/l2 tile
#define BKF  64           // fp32 k-elems per staged tile (2 MFMA K-steps)
#define NKT  (D_ / BKF)   // 12
#define LDH  72           // halves per LDS row (144B: uniform bank spread)

__device__ __forceinline__ unsigned fmap(float f) {
    unsigned u = __float_as_uint(f);
    return (u & 0x80000000u) ? ~u : (u | 0x80000000u);   // monotone float->uint
}
__device__ __forceinline__ float fdecode(unsigned u) {
    return __uint_as_float((u & 0x80000000u) ? (u ^ 0x80000000u) : ~u);
}
__device__ __forceinline__ float wred_max(float v) {
    #pragma unroll
    for (int o = 32; o; o >>= 1) v = fmaxf(v, __shfl_xor(v, o));
    return v;
}
__device__ __forceinline__ float wred_sum(float v) {
    #pragma unroll
    for (int o = 32; o; o >>= 1) v += __shfl_xor(v, o);
    return v;
}

__device__ __forceinline__ f16x8 cvt8(float4 a, float4 b) {
    union { h16x2 h2[4]; f16x8 h8; } u;
    u.h2[0] = __builtin_amdgcn_cvt_pkrtz(a.x, a.y);
    u.h2[1] = __builtin_amdgcn_cvt_pkrtz(a.z, a.w);
    u.h2[2] = __builtin_amdgcn_cvt_pkrtz(b.x, b.y);
    u.h2[3] = __builtin_amdgcn_cvt_pkrtz(b.z, b.w);
    return u.h8;
}

// K1: per (b, ti, tj): 128x128 match tile via fp16 MFMA; masked row/col max.
__global__ __launch_bounds__(512, 2)
void k_match_max(const float* __restrict__ v1, const float* __restrict__ m1,
                 const float* __restrict__ v2, const float* __restrict__ m2,
                 unsigned* __restrict__ ru1, unsigned* __restrict__ ru2)
{
    __shared__ __align__(16) _Float16 As[2][BT * LDH];   // 36.9 KB
    __shared__ __align__(16) _Float16 Bs[2][BT * LDH];   // 36.9 KB
    __shared__ unsigned rU[BT], cU[BT];
    __shared__ float m1s[BT], m2s[BT];

    // bijective XCD swizzle: 512 blocks, 64/XCD -> a batch's 4 blocks on one XCD
    const int bid = blockIdx.x;
    const int wg  = (bid & 7) * 64 + (bid >> 3);
    const int b = wg >> 2, ti = (wg >> 1) & 1, tj = wg & 1;

    const int t = threadIdx.x;
    const int lane = t & 63, w = t >> 6;
    const int wr = w >> 1, wc = w & 1;          // wave sub-tile: 32 rows x 64 cols
    const int fr = lane & 15, fg = lane >> 4;

    if (t < BT) {
        rU[t] = 0u; cU[t] = 0u;                 // 0 == -inf under fmap
        m1s[t] = m1[b * L_ + ti * BT + t];
        m2s[t] = m2[b * L_ + tj * BT + t];
    }

    // staging geometry: thread t owns row (t>>2), fp32 cols [c4*16, c4*16+16)
    // of the current k-tile: 4 float4 loads -> 16 halves -> 2 ds_write_b128.
    const int grow = t >> 2;                    // 0..127
    const int c4   = t & 3;
    const float* ga = v1 + ((size_t)b * L_ + ti * BT + grow) * D_ + c4 * 16;
    const float* gb = v2 + ((size_t)b * L_ + tj * BT + grow) * D_ + c4 * 16;

    float4 ra[4], rb[4];                        // 8 float4 in flight (32 VGPR)

    #define GLOAD(kt) do {                                                    \
        const float* A_ = ga + (kt) * BKF;                                    \
        const float* C_ = gb + (kt) * BKF;                                    \
        ra[0] = *(const float4*)(A_);      ra[1] = *(const float4*)(A_ + 4);  \
        ra[2] = *(const float4*)(A_ + 8);  ra[3] = *(const float4*)(A_ + 12); \
        rb[0] = *(const float4*)(C_);      rb[1] = *(const float4*)(C_ + 4);  \
        rb[2] = *(const float4*)(C_ + 8);  rb[3] = *(const float4*)(C_ + 12); \
    } while (0)

    #define DSWRITE(buf) do {                                                 \
        _Float16* da = &As[buf][grow * LDH + c4 * 16];                        \
        _Float16* db = &Bs[buf][grow * LDH + c4 * 16];                        \
        *(f16x8*)da       = cvt8(ra[0], ra[1]);                               \
        *(f16x8*)(da + 8) = cvt8(ra[2], ra[3]);                               \
        *(f16x8*)db       = cvt8(rb[0], rb[1]);                               \
        *(f16x8*)(db + 8) = cvt8(rb[2], rb[3]);                               \
    } while (0)

    f32x4 acc[2][4] = {};
    GLOAD(0);
    DSWRITE(0);
    __syncthreads();
    int cur = 0;
    for (int kt = 0; kt < NKT; ++kt) {
        if (kt + 1 < NKT) GLOAD(kt + 1);         // issue early (async under MFMA)
        __builtin_amdgcn_sched_barrier(0);       // don't sink the loads
        #pragma unroll
        for (int ks = 0; ks < 2; ++ks) {
            f16x8 af[2], bf[4];
            #pragma unroll
            for (int i = 0; i < 2; ++i) {
                int r1 = wr * 32 + i * 16 + fr;
                af[i] = *(const f16x8*)&As[cur][r1 * LDH + ks * 32 + fg * 8];
            }
            #pragma unroll
            for (int j = 0; j < 4; ++j) {
                int r2 = wc * 64 + j * 16 + fr;
                bf[j] = *(const f16x8*)&Bs[cur][r2 * LDH + ks * 32 + fg * 8];
            }
            #pragma unroll
            for (int i = 0; i < 2; ++i)
                #pragma unroll
                for (int j = 0; j < 4; ++j)
                    acc[i][j] = __builtin_amdgcn_mfma_f32_16x16x32_f16(af[i], bf[j], acc[i][j], 0, 0, 0);
        }
        __builtin_amdgcn_sched_barrier(0);       // keep cvt/ds_write AFTER MFMAs
        if (kt + 1 < NKT) DSWRITE(cur ^ 1);      // vmcnt wait lands here only
        __syncthreads();
        cur ^= 1;
    }
    #undef GLOAD
    #undef DSWRITE

    // masked row-max: C/D layout row = fg*4+reg (+16i), col = fr (+16j)
    #pragma unroll
    for (int i = 0; i < 2; ++i)
        #pragma unroll
        for (int r = 0; r < 4; ++r) {
            int row = wr * 32 + i * 16 + fg * 4 + r;
            bool rv = m1s[row] > 0.f;
            float mx = NEGV;
            #pragma unroll
            for (int j = 0; j < 4; ++j) {
                int col = wc * 64 + j * 16 + fr;
                float vv = (rv && m2s[col] > 0.f) ? acc[i][j][r] : NEGV;
                mx = fmaxf(mx, vv);
            }
            atomicMax(&rU[row], fmap(mx));
        }
    // masked col-max
    #pragma unroll
    for (int j = 0; j < 4; ++j) {
        int col = wc * 64 + j * 16 + fr;
        bool cv = m2s[col] > 0.f;
        float mx = NEGV;
        #pragma unroll
        for (int i = 0; i < 2; ++i)
            #pragma unroll
            for (int r = 0; r < 4; ++r) {
                int row = wr * 32 + i * 16 + fg * 4 + r;
                float vv = (cv && m1s[row] > 0.f) ? acc[i][j][r] : NEGV;
                mx = fmaxf(mx, vv);
            }
        atomicMax(&cU[col], fmap(mx));
    }
    __syncthreads();
    if (t < BT)            atomicMax(&ru1[b * L_ + ti * BT + t], rU[t]);
    else if (t < 2 * BT)   atomicMax(&ru2[b * L_ + tj * BT + (t - BT)], cU[t - BT]);
}

// K2: per (b, side, chunk): softmax over 256 logits (redundant per chunk, cheap)
// + pool of 256 cols. 768 blocks.
__global__ __launch_bounds__(256)
void k_attn_pool(const float* __restrict__ v1, const float* __restrict__ m1,
                 const float* __restrict__ v2, const float* __restrict__ m2,
                 const unsigned* __restrict__ ru1, const unsigned* __restrict__ ru2,
                 float* __restrict__ pout)
{
    // XCD swizzle: 768 blocks -> 96/XCD -> 16 consecutive batches per XCD
    const int lin = (int)blockIdx.x;
    const int swz = (lin & 7) * 96 + (lin >> 3);
    const int b = swz / 6, rem = swz % 6, side = rem / 3, chunk = rem % 3;

    const float* v     = side ? v2 : v1;
    const float* mk    = side ? m2 : m1;
    const unsigned* ru = side ? ru2 : ru1;
    const int t = threadIdx.x, lane = t & 63, w = t >> 6;

    __shared__ float attn[L_];
    __shared__ float sred[4];

    float mkv = mk[b * L_ + t];
    float s = (mkv > 0.f) ? (-fdecode(ru[b * L_ + t]) / 100.0f) : NEGV;

    float wm = wred_max(s);
    if (lane == 0) sred[w] = wm;
    __syncthreads();
    float mx = fmaxf(fmaxf(sred[0], sred[1]), fmaxf(sred[2], sred[3]));
    float e = expf(s - mx);
    __syncthreads();
    float ws = wred_sum(e);
    if (lane == 0) sred[w] = ws;
    __syncthreads();
    float sum = sred[0] + sred[1] + sred[2] + sred[3];
    attn[t] = e / sum;
    __syncthreads();

    const int d = chunk * 256 + t;
    const float* vb = v + (size_t)b * L_ * D_ + d;
    float p = 0.f;
    #pragma unroll 8
    for (int l = 0; l < L_; ++l) p += attn[l] * vb[(size_t)l * D_];
    pout[((size_t)b * 2 + side) * D_ + d] = p;
}

// K3: per batch: cosine similarity of p1, p2.
__global__ __launch_bounds__(256)
void k_cos(const float* __restrict__ pout, float* __restrict__ out)
{
    const int b = blockIdx.x, t = threadIdx.x, lane = t & 63, w = t >> 6;
    const float* p1 = pout + (size_t)b * 2 * D_;
    const float* p2 = p1 + D_;
    float dot = 0.f, n1 = 0.f, n2 = 0.f;
    for (int d = t; d < D_; d += 256) {
        float a = p1[d], c = p2[d];
        dot += a * c; n1 += a * a; n2 += c * c;
    }
    dot = wred_sum(dot); n1 = wred_sum(n1); n2 = wred_sum(n2);
    __shared__ float sd[4], sa[4], sc[4];
    if (lane == 0) { sd[w] = dot; sa[w] = n1; sc[w] = n2; }
    __syncthreads();
    if (t == 0) {
        float dd = sd[0] + sd[1] + sd[2] + sd[3];
        float aa = sa[0] + sa[1] + sa[2] + sa[3];
        float cc = sc[0] + sc[1] + sc[2] + sc[3];
        out[b] = dd / (fmaxf(sqrtf(aa), 1e-8f) * fmaxf(sqrtf(cc), 1e-8f));
    }
}

extern "C" void kernel_launch(void* const* d_in, const int* in_sizes, int n_in,
                              void* d_out, int out_size, void* d_ws, size_t ws_size,
                              hipStream_t stream)
{
    const float* v1 = (const float*)d_in[0];
    const float* m1 = (const float*)d_in[1];
    const float* v2 = (const float*)d_in[2];
    const float* m2 = (const float*)d_in[3];
    float* out = (float*)d_out;

    unsigned* ru1 = (unsigned*)d_ws;                  // [B, L] mapped row-max (side 1)
    unsigned* ru2 = ru1 + (size_t)B_ * L_;            // [B, L] mapped col-max (side 2)
    float*    pout = (float*)(ru2 + (size_t)B_ * L_); // [B, 2, D] pooled vectors

    (void)hipMemsetAsync(d_ws, 0, 2 * (size_t)B_ * L_ * sizeof(unsigned), stream);

    k_match_max<<<dim3((L_ / BT) * (L_ / BT) * B_), 512, 0, stream>>>(v1, m1, v2, m2, ru1, ru2);

    k_attn_pool<<<dim3(B_ * 2 * 3), 256, 0, stream>>>(v1, m1, v2, m2, ru1, ru2, pout);

    k_cos<<<B_, 256, 0, stream>>>(pout, out);
}